// Round 1
// baseline (777.047 us; speedup 1.0000x reference)
//
#include <hip/hip_runtime.h>
#include <cstdint>

#define NDIM 512
#define DDIM 128
#define NN (512 * 512)

typedef unsigned short u16;
typedef short bf16x8 __attribute__((ext_vector_type(8)));
typedef float f32x4 __attribute__((ext_vector_type(4)));

union I4U { int4 v; u16 s[8]; };

__device__ __forceinline__ u16 f2bf(float f) {
  unsigned u = __builtin_bit_cast(unsigned, f);
  u += 0x7fffu + ((u >> 16) & 1u);           // RNE
  return (u16)(u >> 16);
}
__device__ __forceinline__ float bf2f(u16 s) {
  return __builtin_bit_cast(float, ((unsigned)s) << 16);
}
__device__ __forceinline__ float sigm(float x) {
  return 1.0f / (1.0f + __expf(-x));
}
__device__ __forceinline__ void gload16(void* lds_base, const void* gsrc) {
  __builtin_amdgcn_global_load_lds((const __attribute__((address_space(1))) void*)gsrc,
                                   (__attribute__((address_space(3))) void*)lds_base,
                                   16, 0, 0);
}

// ---------------- kernel 0: weights fp32 -> bf16 ----------------
// Wbig rows: [0,256)=wp, [256,512)=wg, [512,640)=w_gate. Wout = w_out. All [row][128].
__global__ __launch_bounds__(256) void k_prep(const float* __restrict__ wp,
                                              const float* __restrict__ wg,
                                              const float* __restrict__ wga,
                                              const float* __restrict__ wo,
                                              u16* __restrict__ Wbig, u16* __restrict__ Wout) {
  int i = blockIdx.x * 256 + threadIdx.x;    // 0..98303
  if (i < 640 * 128) {
    int r = i >> 7, c = i & 127;
    float v = (r < 256) ? wp[r * 128 + c] : (r < 512) ? wg[(r - 256) * 128 + c]
                                                      : wga[(r - 512) * 128 + c];
    Wbig[i] = f2bf(v);
  } else {
    int j = i - 640 * 128;                   // 0..16383
    Wout[j] = f2bf(wo[j]);
  }
}

// ---------------- kernel 1: LN(z) -> h; p,g,gate; a_t,b_t (d-major), gate ----------------
// block: 64 ij rows, 512 threads (8 waves: wr=wave>>1 row-quad, wc=wave&1 col-half)
__global__ __launch_bounds__(512) void k_pass1(
    const float* __restrict__ z, const float* __restrict__ mask,
    const float* __restrict__ niw, const float* __restrict__ nib,
    const u16* __restrict__ Wbig,
    u16* __restrict__ a_t, u16* __restrict__ b_t, u16* __restrict__ gate) {
  __shared__ __align__(16) char lds[32768];
  const int t = threadIdx.x;
  const int ij0 = blockIdx.x * 64;

  // ---- phase A: LN over D=128 per row; h -> lds[0:16K) as [64][256B] bf16, XOR-swizzled
  {
    const int row = t >> 3, seg = t & 7;     // 8 threads/row, 16 elems each
    const float4* zp = (const float4*)(z + (size_t)(ij0 + row) * 128 + seg * 16);
    float zv[16];
    {
      float4 a0 = zp[0], a1 = zp[1], a2 = zp[2], a3 = zp[3];
      zv[0]=a0.x; zv[1]=a0.y; zv[2]=a0.z; zv[3]=a0.w;
      zv[4]=a1.x; zv[5]=a1.y; zv[6]=a1.z; zv[7]=a1.w;
      zv[8]=a2.x; zv[9]=a2.y; zv[10]=a2.z; zv[11]=a2.w;
      zv[12]=a3.x; zv[13]=a3.y; zv[14]=a3.z; zv[15]=a3.w;
    }
    float s = 0.f, ss = 0.f;
#pragma unroll
    for (int j = 0; j < 16; j++) { s += zv[j]; ss += zv[j] * zv[j]; }
    s += __shfl_xor(s, 1); s += __shfl_xor(s, 2); s += __shfl_xor(s, 4);
    ss += __shfl_xor(ss, 1); ss += __shfl_xor(ss, 2); ss += __shfl_xor(ss, 4);
    const float mu = s * (1.f / 128.f);
    const float var = ss * (1.f / 128.f) - mu * mu;
    const float rs = rsqrtf(var + 1e-5f);
    float wv_[16], bv_[16];
    {
      const float4* wq = (const float4*)(niw + seg * 16);
      const float4* bq = (const float4*)(nib + seg * 16);
      float4 w0=wq[0],w1=wq[1],w2=wq[2],w3=wq[3], b0=bq[0],b1=bq[1],b2=bq[2],b3=bq[3];
      wv_[0]=w0.x;wv_[1]=w0.y;wv_[2]=w0.z;wv_[3]=w0.w; wv_[4]=w1.x;wv_[5]=w1.y;wv_[6]=w1.z;wv_[7]=w1.w;
      wv_[8]=w2.x;wv_[9]=w2.y;wv_[10]=w2.z;wv_[11]=w2.w; wv_[12]=w3.x;wv_[13]=w3.y;wv_[14]=w3.z;wv_[15]=w3.w;
      bv_[0]=b0.x;bv_[1]=b0.y;bv_[2]=b0.z;bv_[3]=b0.w; bv_[4]=b1.x;bv_[5]=b1.y;bv_[6]=b1.z;bv_[7]=b1.w;
      bv_[8]=b2.x;bv_[9]=b2.y;bv_[10]=b2.z;bv_[11]=b2.w; bv_[12]=b3.x;bv_[13]=b3.y;bv_[14]=b3.z;bv_[15]=b3.w;
    }
    I4U p0, p1;
#pragma unroll
    for (int j = 0; j < 8; j++) p0.s[j] = f2bf((zv[j] - mu) * rs * wv_[j] + bv_[j]);
#pragma unroll
    for (int j = 0; j < 8; j++) p1.s[j] = f2bf((zv[8 + j] - mu) * rs * wv_[8 + j] + bv_[8 + j]);
    char* base = lds + row * 256;
    const int sw = (row & 7) << 4;
    *(int4*)(base + ((seg * 32) ^ sw)) = p0.v;
    *(int4*)(base + ((seg * 32 + 16) ^ sw)) = p1.v;
  }
  __syncthreads();

  // ---- phase B: MFMA, M=16/wave, N=320/wave (20 tiles), K=128
  const int wv = t >> 6, l = t & 63;
  const int wr = wv >> 1, wc = wv & 1;
  const int l15 = l & 15, l4 = l >> 4;
  f32x4 acc[20];
#pragma unroll
  for (int i = 0; i < 20; i++) acc[i] = (f32x4){0.f, 0.f, 0.f, 0.f};
  const int arow = wr * 16 + l15;
  const char* abase = lds + arow * 256;
  const int asw = (arow & 7) << 4;
  const char* wbase = (const char*)Wbig + l15 * 256 + l4 * 16;
#pragma unroll
  for (int ks = 0; ks < 4; ks++) {
    bf16x8 af = *(const bf16x8*)(abase + ((ks * 64 + l4 * 16) ^ asw));
#pragma unroll
    for (int idx = 0; idx < 20; idx++) {
      const int ct = (idx < 8) ? (wc * 8 + idx)
                   : (idx < 16) ? (16 + wc * 8 + (idx - 8))
                                : (32 + wc * 4 + (idx - 16));
      bf16x8 bfr = *(const bf16x8*)(wbase + ct * 4096 + ks * 64);
      acc[idx] = __builtin_amdgcn_mfma_f32_16x16x32_bf16(af, bfr, acc[idx], 0, 0, 0);
    }
  }
  __syncthreads();   // lds (h) dead; reuse for a/b transpose staging

  // ---- phase C: epilogue. ab = p*sigmoid(g)*mask -> stage [d][ij] (16KB each half); gate direct.
  const int ijb = wr * 16 + (l4 << 2);
  float mk[4];
#pragma unroll
  for (int r = 0; r < 4; r++) mk[r] = mask[ij0 + ijb + r];
  char* sX = lds + wc * 16384;               // wc0 -> a-stage, wc1 -> b-stage
#pragma unroll
  for (int i = 0; i < 8; i++) {
    const int d = i * 16 + l15;
    u16 pk[4];
#pragma unroll
    for (int r = 0; r < 4; r++)
      pk[r] = f2bf(acc[i][r] * sigm(acc[8 + i][r]) * mk[r]);
    unsigned long long uu = (unsigned)(pk[0] | ((unsigned)pk[1] << 16));
    uu |= ((unsigned long long)(unsigned)(pk[2] | ((unsigned)pk[3] << 16))) << 32;
    *(unsigned long long*)(sX + d * 128 + (((ijb * 2)) ^ ((d & 7) << 3))) = uu;
  }
#pragma unroll
  for (int gt = 0; gt < 4; gt++) {
    const int e = wc * 64 + gt * 16 + l15;
#pragma unroll
    for (int r = 0; r < 4; r++)
      gate[(size_t)(ij0 + ijb + r) * 128 + e] = f2bf(sigm(acc[16 + gt][r]));
  }
  __syncthreads();

  // ---- phase D: coalesced store of a_t/b_t (d-major)
  {
    const int mb = t >> 8;                   // 0=a, 1=b
    const int tt = t & 255;
    const int d = tt >> 1, q = tt & 1;
    const char* sS = lds + mb * 16384;
    const int dsw = (d & 7) << 3;
    unsigned long long u[8];
#pragma unroll
    for (int m = 0; m < 8; m++)
      u[m] = *(const unsigned long long*)(sS + d * 128 + ((q * 64 + m * 8) ^ dsw));
    u16* dst = (mb ? b_t : a_t) + (size_t)d * NN + ij0 + q * 32;
#pragma unroll
    for (int m = 0; m < 4; m++) {
      int4 v;
      v.x = (int)(u[2 * m] & 0xffffffffull); v.y = (int)(u[2 * m] >> 32);
      v.z = (int)(u[2 * m + 1] & 0xffffffffull); v.w = (int)(u[2 * m + 1] >> 32);
      ((int4*)dst)[m] = v;
    }
  }
}

// ---------------- kernel 2: x_t[d] = a_t[d] @ b_t[d]^T, 128 batched 512^3 GEMMs ----------------
__global__ __launch_bounds__(256) void k_pass2(const u16* __restrict__ a_t,
                                               const u16* __restrict__ b_t,
                                               u16* __restrict__ x_t) {
  __shared__ __align__(16) char lds[32768];
  // XCD-chunked swizzle: nwg=2048 (divisible by 8) -> XCD x gets 16 consecutive d's
  const int b2 = ((int)blockIdx.x & 7) * 256 + ((int)blockIdx.x >> 3);
  const int d = b2 >> 4;
  const int tile = b2 & 15;
  const int row0 = (tile >> 2) * 128, col0 = (tile & 3) * 128;
  const char* A = (const char*)(a_t + (size_t)d * NN);
  const char* B = (const char*)(b_t + (size_t)d * NN);
  const int t = threadIdx.x;
  const int wv = t >> 6, l = t & 63;
  const int wr = wv >> 1, wc = wv & 1;
  const int l15 = l & 15, l4 = l >> 4;
  char* al = lds;
  char* bl = lds + 16384;
  f32x4 acc[4][4];
#pragma unroll
  for (int m = 0; m < 4; m++)
#pragma unroll
    for (int n = 0; n < 4; n++) acc[m][n] = (f32x4){0.f, 0.f, 0.f, 0.f};

  for (int ks = 0; ks < 8; ks++) {
#pragma unroll
    for (int it = 0; it < 4; it++) {
      const int f = it * 256 + t;            // t = wv*64 + l
      const int row = f >> 3, kc = f & 7;
      const int ldsoff = (it * 256 + wv * 64) * 16;   // wave-uniform base, lane adds l*16
      gload16(al + ldsoff, A + (size_t)(row0 + row) * 1024 + ks * 128 + kc * 16);
      gload16(bl + ldsoff, B + (size_t)(col0 + row) * 1024 + ks * 128 + kc * 16);
    }
    __syncthreads();
#pragma unroll
    for (int kk = 0; kk < 2; kk++) {
      bf16x8 af[4], bfr[4];
#pragma unroll
      for (int m = 0; m < 4; m++)
        af[m] = *(const bf16x8*)(al + (wr * 64 + m * 16 + l15) * 128 + kk * 64 + l4 * 16);
#pragma unroll
      for (int n = 0; n < 4; n++)
        bfr[n] = *(const bf16x8*)(bl + (wc * 64 + n * 16 + l15) * 128 + kk * 64 + l4 * 16);
#pragma unroll
      for (int m = 0; m < 4; m++)
#pragma unroll
        for (int n = 0; n < 4; n++)
          acc[m][n] = __builtin_amdgcn_mfma_f32_16x16x32_bf16(af[m], bfr[n], acc[m][n], 0, 0, 0);
    }
    __syncthreads();
  }
  // epilogue: stage C [128][256B] swizzled -> coalesced bf16 stores
#pragma unroll
  for (int m = 0; m < 4; m++) {
#pragma unroll
    for (int r = 0; r < 4; r++) {
      const int row = wr * 64 + m * 16 + l4 * 4 + r;
      const int sw = (row & 7) << 4;
      char* rowp = lds + row * 256;
#pragma unroll
      for (int n = 0; n < 4; n++) {
        const int col = wc * 64 + n * 16 + l15;
        *(short*)(rowp + ((col * 2) ^ sw)) = (short)f2bf(acc[m][n][r]);
      }
    }
  }
  __syncthreads();
  {
    const int row = t >> 1, q = t & 1;
    const int sw = (row & 7) << 4;
    const char* rowp = lds + row * 256;
    int4 v[8];
#pragma unroll
    for (int c = 0; c < 8; c++)
      v[c] = *(const int4*)(rowp + ((q * 128 + c * 16) ^ sw));
    u16* dst = x_t + (size_t)d * NN + (size_t)(row0 + row) * 512 + col0 + q * 64;
#pragma unroll
    for (int c = 0; c < 8; c++) ((int4*)dst)[c] = v[c];
  }
}

// ---------------- kernel 3: transpose x_t -> LN -> @w_out^T -> * gate ----------------
__global__ __launch_bounds__(256) void k_pass3(const u16* __restrict__ x_t,
                                               const u16* __restrict__ gate,
                                               const float* __restrict__ now_,
                                               const float* __restrict__ nob,
                                               const u16* __restrict__ Wout,
                                               float* __restrict__ out) {
  __shared__ __align__(16) char xl[16384];   // [64 ij][256B d] bf16, swizzled
  const int t = threadIdx.x;
  const int ij0 = blockIdx.x * 64;
  // ---- phase A: gather d-major -> (ij,d) LDS
  {
    const int d = t >> 1, q = t & 1;
    const int4* src = (const int4*)(x_t + (size_t)d * NN + ij0 + q * 32);
#pragma unroll
    for (int c = 0; c < 4; c++) {
      I4U v; v.v = src[c];
#pragma unroll
      for (int j = 0; j < 8; j++) {
        const int ij = q * 32 + c * 8 + j;
        *(short*)(xl + ij * 256 + ((2 * d) ^ ((ij & 7) << 4))) = (short)v.s[j];
      }
    }
  }
  __syncthreads();
  // ---- phase B: LN over d per ij row (4 threads/row)
  {
    const int row = t >> 2, seg = t & 3;
    char* base = xl + row * 256;
    const int sw = (row & 7) << 4;
    float f[32];
#pragma unroll
    for (int c = 0; c < 4; c++) {
      I4U v; v.v = *(const int4*)(base + ((seg * 64 + c * 16) ^ sw));
#pragma unroll
      for (int j = 0; j < 8; j++) f[c * 8 + j] = bf2f(v.s[j]);
    }
    float s = 0.f, ss = 0.f;
#pragma unroll
    for (int j = 0; j < 32; j++) { s += f[j]; ss += f[j] * f[j]; }
    s += __shfl_xor(s, 1); s += __shfl_xor(s, 2);
    ss += __shfl_xor(ss, 1); ss += __shfl_xor(ss, 2);
    const float mu = s * (1.f / 128.f);
    const float var = ss * (1.f / 128.f) - mu * mu;
    const float rs = rsqrtf(var + 1e-5f);
#pragma unroll
    for (int c = 0; c < 4; c++) {
      const float4 w0 = *(const float4*)(now_ + seg * 32 + c * 8);
      const float4 w1 = *(const float4*)(now_ + seg * 32 + c * 8 + 4);
      const float4 b0 = *(const float4*)(nob + seg * 32 + c * 8);
      const float4 b1 = *(const float4*)(nob + seg * 32 + c * 8 + 4);
      I4U o;
      o.s[0] = f2bf((f[c*8+0] - mu) * rs * w0.x + b0.x);
      o.s[1] = f2bf((f[c*8+1] - mu) * rs * w0.y + b0.y);
      o.s[2] = f2bf((f[c*8+2] - mu) * rs * w0.z + b0.z);
      o.s[3] = f2bf((f[c*8+3] - mu) * rs * w0.w + b0.w);
      o.s[4] = f2bf((f[c*8+4] - mu) * rs * w1.x + b1.x);
      o.s[5] = f2bf((f[c*8+5] - mu) * rs * w1.y + b1.y);
      o.s[6] = f2bf((f[c*8+6] - mu) * rs * w1.z + b1.z);
      o.s[7] = f2bf((f[c*8+7] - mu) * rs * w1.w + b1.w);
      *(int4*)(base + ((seg * 64 + c * 16) ^ sw)) = o.v;
    }
  }
  __syncthreads();
  // ---- phase C: out = (xln @ Wout^T) * gate
  const int wv = t >> 6, l = t & 63;
  const int l15 = l & 15, l4 = l >> 4;
  const int arow = wv * 16 + l15;
  const char* abase = xl + arow * 256;
  const int asw = (arow & 7) << 4;
  const char* wbase = (const char*)Wout + l15 * 256 + l4 * 16;
  f32x4 acc[8];
#pragma unroll
  for (int n = 0; n < 8; n++) acc[n] = (f32x4){0.f, 0.f, 0.f, 0.f};
#pragma unroll
  for (int ks = 0; ks < 4; ks++) {
    bf16x8 af = *(const bf16x8*)(abase + ((ks * 64 + l4 * 16) ^ asw));
#pragma unroll
    for (int n = 0; n < 8; n++) {
      bf16x8 bfr = *(const bf16x8*)(wbase + n * 4096 + ks * 64);
      acc[n] = __builtin_amdgcn_mfma_f32_16x16x32_bf16(af, bfr, acc[n], 0, 0, 0);
    }
  }
  const int rowb = wv * 16 + (l4 << 2);
#pragma unroll
  for (int n = 0; n < 8; n++) {
    const int e = n * 16 + l15;
#pragma unroll
    for (int r = 0; r < 4; r++) {
      const size_t idx = (size_t)(ij0 + rowb + r) * 128 + e;
      out[idx] = acc[n][r] * bf2f(gate[idx]);
    }
  }
}

// ---------------- launch ----------------
extern "C" void kernel_launch(void* const* d_in, const int* in_sizes, int n_in,
                              void* d_out, int out_size, void* d_ws, size_t ws_size,
                              hipStream_t stream) {
  const float* z    = (const float*)d_in[0];
  const float* mask = (const float*)d_in[1];
  const float* niw  = (const float*)d_in[2];
  const float* nib  = (const float*)d_in[3];
  const float* wp   = (const float*)d_in[4];
  const float* wg   = (const float*)d_in[5];
  const float* now_ = (const float*)d_in[6];
  const float* nob  = (const float*)d_in[7];
  const float* wo   = (const float*)d_in[8];
  const float* wga  = (const float*)d_in[9];
  float* out = (float*)d_out;
  char* ws = (char*)d_ws;

  u16* Wbig = (u16*)ws;                                   // 160 KB
  u16* Wout = (u16*)(ws + 0x28000);                       // 32 KB
  u16* a_t  = (u16*)(ws + 0x100000);                      // 64 MB  (D,N,N) bf16
  u16* b_t  = (u16*)(ws + 0x100000 + 0x4000000);          // 64 MB
  u16* x_t  = (u16*)(ws + 0x100000 + 0x8000000);          // 64 MB
  u16* gate = (u16*)(ws + 0x100000 + 0xC000000);          // 64 MB  (N*N, D) bf16

  hipLaunchKernelGGL(k_prep, dim3(384), dim3(256), 0, stream, wp, wg, wga, wo, Wbig, Wout);
  hipLaunchKernelGGL(k_pass1, dim3(4096), dim3(512), 0, stream, z, mask, niw, nib, Wbig, a_t, b_t, gate);
  hipLaunchKernelGGL(k_pass2, dim3(2048), dim3(256), 0, stream, a_t, b_t, x_t);
  hipLaunchKernelGGL(k_pass3, dim3(4096), dim3(256), 0, stream, x_t, gate, now_, nob, Wout, out);
  (void)in_sizes; (void)n_in; (void)out_size; (void)ws_size;
}

// Round 5
// 705.807 us; speedup vs baseline: 1.1009x; 1.1009x over previous
//
#include <hip/hip_runtime.h>
#include <cstdint>

#define NDIM 512
#define DDIM 128
#define NN (512 * 512)

typedef unsigned short u16;
typedef short bf16x8 __attribute__((ext_vector_type(8)));
typedef float f32x4 __attribute__((ext_vector_type(4)));

union I4U { int4 v; u16 s[8]; };

__device__ __forceinline__ u16 f2bf(float f) {
  unsigned u = __builtin_bit_cast(unsigned, f);
  u += 0x7fffu + ((u >> 16) & 1u);           // RNE
  return (u16)(u >> 16);
}
__device__ __forceinline__ float bf2f(u16 s) {
  return __builtin_bit_cast(float, ((unsigned)s) << 16);
}
__device__ __forceinline__ float sigm(float x) {
  return 1.0f / (1.0f + __expf(-x));
}
__device__ __forceinline__ void gload16(void* lds_base, const void* gsrc) {
  __builtin_amdgcn_global_load_lds((const __attribute__((address_space(1))) void*)gsrc,
                                   (__attribute__((address_space(3))) void*)lds_base,
                                   16, 0, 0);
}

// ---------------- kernel 0: weights fp32 -> bf16 ----------------
// Wbig rows: [0,256)=wp, [256,512)=wg, [512,640)=w_gate. Wout = w_out. All [row][128].
__global__ __launch_bounds__(256) void k_prep(const float* __restrict__ wp,
                                              const float* __restrict__ wg,
                                              const float* __restrict__ wga,
                                              const float* __restrict__ wo,
                                              u16* __restrict__ Wbig, u16* __restrict__ Wout) {
  int i = blockIdx.x * 256 + threadIdx.x;    // 0..98303
  if (i < 640 * 128) {
    int r = i >> 7, c = i & 127;
    float v = (r < 256) ? wp[r * 128 + c] : (r < 512) ? wg[(r - 256) * 128 + c]
                                                      : wga[(r - 512) * 128 + c];
    Wbig[i] = f2bf(v);
  } else {
    int j = i - 640 * 128;                   // 0..16383
    Wout[j] = f2bf(wo[j]);
  }
}

// ---------------- kernel 1: LN(z) -> h; p,g,gate; a_t,b_t (d-major), gate ----------------
// 512 threads (8 waves). wr=wv&3 -> m-tile (16 rows), wc=wv>>2 -> col half.
// Per-wave: A-frags held in regs (16 VGPR); 4 quarters of 64 e-cols with only
// 16 acc VGPRs live -> compiler can deep-prefetch the Wbig B-fragment loads.
__global__ __launch_bounds__(512) void k_pass1(
    const float* __restrict__ z, const float* __restrict__ mask,
    const float* __restrict__ niw, const float* __restrict__ nib,
    const u16* __restrict__ Wbig,
    u16* __restrict__ a_t, u16* __restrict__ b_t, u16* __restrict__ gate) {
  __shared__ __align__(16) char lds[49152];  // [0,16K): h / gate-stage; [16K,48K): a/b stage (4x8KB)
  const int t = threadIdx.x;
  const int ij0 = blockIdx.x * 64;

  // ---- phase A: LN over D=128 per row; h -> lds[0:16K) as [64][256B] bf16, XOR-swizzled
  {
    const int row = t >> 3, seg = t & 7;     // 8 threads/row, 16 elems each
    const float4* zp = (const float4*)(z + (size_t)(ij0 + row) * 128 + seg * 16);
    float zv[16];
    {
      float4 a0 = zp[0], a1 = zp[1], a2 = zp[2], a3 = zp[3];
      zv[0]=a0.x; zv[1]=a0.y; zv[2]=a0.z; zv[3]=a0.w;
      zv[4]=a1.x; zv[5]=a1.y; zv[6]=a1.z; zv[7]=a1.w;
      zv[8]=a2.x; zv[9]=a2.y; zv[10]=a2.z; zv[11]=a2.w;
      zv[12]=a3.x; zv[13]=a3.y; zv[14]=a3.z; zv[15]=a3.w;
    }
    float s = 0.f, ss = 0.f;
#pragma unroll
    for (int j = 0; j < 16; j++) { s += zv[j]; ss += zv[j] * zv[j]; }
    s += __shfl_xor(s, 1); s += __shfl_xor(s, 2); s += __shfl_xor(s, 4);
    ss += __shfl_xor(ss, 1); ss += __shfl_xor(ss, 2); ss += __shfl_xor(ss, 4);
    const float mu = s * (1.f / 128.f);
    const float var = ss * (1.f / 128.f) - mu * mu;
    const float rs = rsqrtf(var + 1e-5f);
    float wv_[16], bv_[16];
    {
      const float4* wq = (const float4*)(niw + seg * 16);
      const float4* bq = (const float4*)(nib + seg * 16);
      float4 w0=wq[0],w1=wq[1],w2=wq[2],w3=wq[3], b0=bq[0],b1=bq[1],b2=bq[2],b3=bq[3];
      wv_[0]=w0.x;wv_[1]=w0.y;wv_[2]=w0.z;wv_[3]=w0.w; wv_[4]=w1.x;wv_[5]=w1.y;wv_[6]=w1.z;wv_[7]=w1.w;
      wv_[8]=w2.x;wv_[9]=w2.y;wv_[10]=w2.z;wv_[11]=w2.w; wv_[12]=w3.x;wv_[13]=w3.y;wv_[14]=w3.z;wv_[15]=w3.w;
      bv_[0]=b0.x;bv_[1]=b0.y;bv_[2]=b0.z;bv_[3]=b0.w; bv_[4]=b1.x;bv_[5]=b1.y;bv_[6]=b1.z;bv_[7]=b1.w;
      bv_[8]=b2.x;bv_[9]=b2.y;bv_[10]=b2.z;bv_[11]=b2.w; bv_[12]=b3.x;bv_[13]=b3.y;bv_[14]=b3.z;bv_[15]=b3.w;
    }
    I4U p0, p1;
#pragma unroll
    for (int j = 0; j < 8; j++) p0.s[j] = f2bf((zv[j] - mu) * rs * wv_[j] + bv_[j]);
#pragma unroll
    for (int j = 0; j < 8; j++) p1.s[j] = f2bf((zv[8 + j] - mu) * rs * wv_[8 + j] + bv_[8 + j]);
    char* base = lds + row * 256;
    const int sw = (row & 7) << 4;
    *(int4*)(base + ((seg * 32) ^ sw)) = p0.v;
    *(int4*)(base + ((seg * 32 + 16) ^ sw)) = p1.v;
  }
  __syncthreads();

  const int wv = t >> 6, l = t & 63;
  const int wr = wv & 3, wc = wv >> 2;
  const int l15 = l & 15, l4 = l >> 4;

  // ---- A-fragments: load once, hold (16 VGPR)
  const int arow = wr * 16 + l15;
  const char* abase = lds + arow * 256;
  const int asw = (arow & 7) << 4;
  bf16x8 af[4];
#pragma unroll
  for (int ks = 0; ks < 4; ks++)
    af[ks] = *(const bf16x8*)(abase + ((ks * 64 + l4 * 16) ^ asw));

  const char* wbase = (const char*)Wbig + l15 * 256 + l4 * 16;
  const int ijl = wr * 16 + l4 * 4;          // local row base (4 rows per lane)
  float mk[4];
#pragma unroll
  for (int r = 0; r < 4; r++) mk[r] = mask[ij0 + ijl + r];

  char* stage = lds + 16384;

  // ---- 4 quarters of 64 e-cols: p & g MFMAs, fuse, stage d-major
#pragma unroll
  for (int q = 0; q < 4; q++) {
    f32x4 ap[2], ag[2];
#pragma unroll
    for (int s = 0; s < 2; s++) { ap[s] = (f32x4){0,0,0,0}; ag[s] = (f32x4){0,0,0,0}; }
#pragma unroll
    for (int s = 0; s < 2; s++) {
      const int ctp = 4 * q + 2 * wc + s;
#pragma unroll
      for (int ks = 0; ks < 4; ks++) {
        bf16x8 bp = *(const bf16x8*)(wbase + ctp * 4096 + ks * 64);
        ap[s] = __builtin_amdgcn_mfma_f32_16x16x32_bf16(af[ks], bp, ap[s], 0, 0, 0);
        bf16x8 bg = *(const bf16x8*)(wbase + (16 + ctp) * 4096 + ks * 64);
        ag[s] = __builtin_amdgcn_mfma_f32_16x16x32_bf16(af[ks], bg, ag[s], 0, 0, 0);
      }
    }
#pragma unroll
    for (int s = 0; s < 2; s++) {
      const int cl = 32 * wc + s * 16 + l15;   // local col within quarter [0,64)
      u16 pk[4];
#pragma unroll
      for (int r = 0; r < 4; r++)
        pk[r] = f2bf(ap[s][r] * sigm(ag[s][r]) * mk[r]);
      unsigned long long uu = (unsigned)(pk[0] | ((unsigned)pk[1] << 16));
      uu |= ((unsigned long long)(unsigned)(pk[2] | ((unsigned)pk[3] << 16))) << 32;
      *(unsigned long long*)(stage + q * 8192 + cl * 128 + ((ijl * 2) ^ ((cl & 7) << 4))) = uu;
    }
  }
  __syncthreads();

  // ---- coalesced a_t/b_t stores (128B per d-row) + gate MFMAs overlapped
  {
    const int col = t >> 3, seg = t & 7;
    const int sw = (col & 7) << 4;
#pragma unroll
    for (int qq = 0; qq < 4; qq++) {
      int4 v = *(const int4*)(stage + qq * 8192 + col * 128 + ((seg * 16) ^ sw));
      u16* dst = (qq < 2 ? a_t : b_t) + (size_t)((qq & 1) * 64 + col) * NN + ij0 + seg * 8;
      *(int4*)dst = v;
    }
  }

  // gate = sigmoid(h @ w_gate^T): reuse held af; h-LDS region becomes stage
  f32x4 gc[4];
#pragma unroll
  for (int s2 = 0; s2 < 4; s2++) gc[s2] = (f32x4){0,0,0,0};
#pragma unroll
  for (int s2 = 0; s2 < 4; s2++) {
    const int ct = 32 + 4 * wc + s2;
#pragma unroll
    for (int ks = 0; ks < 4; ks++) {
      bf16x8 bg = *(const bf16x8*)(wbase + ct * 4096 + ks * 64);
      gc[s2] = __builtin_amdgcn_mfma_f32_16x16x32_bf16(af[ks], bg, gc[s2], 0, 0, 0);
    }
  }
#pragma unroll
  for (int s2 = 0; s2 < 4; s2++) {
    const int col2 = 2 * (64 * wc + 16 * s2 + l15);
#pragma unroll
    for (int r = 0; r < 4; r++) {
      const int row = ijl + r;
      *(u16*)(lds + row * 256 + (col2 ^ ((row & 7) << 4))) = f2bf(sigm(gc[s2][r]));
    }
  }
  __syncthreads();
  {
    const int row = t >> 3, seg = t & 7;
    const int sw = (row & 7) << 4;
    int4 v0 = *(const int4*)(lds + row * 256 + ((seg * 32) ^ sw));
    int4 v1 = *(const int4*)(lds + row * 256 + ((seg * 32 + 16) ^ sw));
    u16* gdst = gate + (size_t)(ij0 + row) * 128 + seg * 16;
    ((int4*)gdst)[0] = v0;
    ((int4*)gdst)[1] = v1;
  }
}

// ---------------- kernel 2: x_t[d] = a_t[d] @ b_t[d]^T, 128 batched 512^3 GEMMs ----------------
__global__ __launch_bounds__(256) void k_pass2(const u16* __restrict__ a_t,
                                               const u16* __restrict__ b_t,
                                               u16* __restrict__ x_t) {
  __shared__ __align__(16) char lds[32768];
  // XCD-chunked swizzle: nwg=2048 (divisible by 8) -> XCD x gets 16 consecutive d's
  const int b2 = ((int)blockIdx.x & 7) * 256 + ((int)blockIdx.x >> 3);
  const int d = b2 >> 4;
  const int tile = b2 & 15;
  const int row0 = (tile >> 2) * 128, col0 = (tile & 3) * 128;
  const char* A = (const char*)(a_t + (size_t)d * NN);
  const char* B = (const char*)(b_t + (size_t)d * NN);
  const int t = threadIdx.x;
  const int wv = t >> 6, l = t & 63;
  const int wr = wv >> 1, wc = wv & 1;
  const int l15 = l & 15, l4 = l >> 4;
  char* al = lds;
  char* bl = lds + 16384;
  f32x4 acc[4][4];
#pragma unroll
  for (int m = 0; m < 4; m++)
#pragma unroll
    for (int n = 0; n < 4; n++) acc[m][n] = (f32x4){0.f, 0.f, 0.f, 0.f};

  for (int ks = 0; ks < 8; ks++) {
#pragma unroll
    for (int it = 0; it < 4; it++) {
      const int f = it * 256 + t;            // t = wv*64 + l
      const int row = f >> 3, kc = f & 7;
      const int ldsoff = (it * 256 + wv * 64) * 16;   // wave-uniform base, lane adds l*16
      gload16(al + ldsoff, A + (size_t)(row0 + row) * 1024 + ks * 128 + kc * 16);
      gload16(bl + ldsoff, B + (size_t)(col0 + row) * 1024 + ks * 128 + kc * 16);
    }
    __syncthreads();
#pragma unroll
    for (int kk = 0; kk < 2; kk++) {
      bf16x8 af[4], bfr[4];
#pragma unroll
      for (int m = 0; m < 4; m++)
        af[m] = *(const bf16x8*)(al + (wr * 64 + m * 16 + l15) * 128 + kk * 64 + l4 * 16);
#pragma unroll
      for (int n = 0; n < 4; n++)
        bfr[n] = *(const bf16x8*)(bl + (wc * 64 + n * 16 + l15) * 128 + kk * 64 + l4 * 16);
#pragma unroll
      for (int m = 0; m < 4; m++)
#pragma unroll
        for (int n = 0; n < 4; n++)
          acc[m][n] = __builtin_amdgcn_mfma_f32_16x16x32_bf16(af[m], bfr[n], acc[m][n], 0, 0, 0);
    }
    __syncthreads();
  }
  // epilogue: stage C [128][256B] swizzled -> coalesced bf16 stores
#pragma unroll
  for (int m = 0; m < 4; m++) {
#pragma unroll
    for (int r = 0; r < 4; r++) {
      const int row = wr * 64 + m * 16 + l4 * 4 + r;
      const int sw = (row & 7) << 4;
      char* rowp = lds + row * 256;
#pragma unroll
      for (int n = 0; n < 4; n++) {
        const int col = wc * 64 + n * 16 + l15;
        *(short*)(rowp + ((col * 2) ^ sw)) = (short)f2bf(acc[m][n][r]);
      }
    }
  }
  __syncthreads();
  {
    const int row = t >> 1, q = t & 1;
    const int sw = (row & 7) << 4;
    const char* rowp = lds + row * 256;
    int4 v[8];
#pragma unroll
    for (int c = 0; c < 8; c++)
      v[c] = *(const int4*)(rowp + ((q * 128 + c * 16) ^ sw));
    u16* dst = x_t + (size_t)d * NN + (size_t)(row0 + row) * 512 + col0 + q * 64;
#pragma unroll
    for (int c = 0; c < 8; c++) ((int4*)dst)[c] = v[c];
  }
}

// ---------------- kernel 3: transpose x_t -> LN -> @w_out^T -> * gate ----------------
__global__ __launch_bounds__(256) void k_pass3(const u16* __restrict__ x_t,
                                               const u16* __restrict__ gate,
                                               const float* __restrict__ now_,
                                               const float* __restrict__ nob,
                                               const u16* __restrict__ Wout,
                                               float* __restrict__ out) {
  __shared__ __align__(16) char xl[16384];   // [64 ij][256B d] bf16, swizzled
  const int t = threadIdx.x;
  const int ij0 = blockIdx.x * 64;
  // ---- phase A: gather d-major -> (ij,d) LDS
  {
    const int d = t >> 1, q = t & 1;
    const int4* src = (const int4*)(x_t + (size_t)d * NN + ij0 + q * 32);
#pragma unroll
    for (int c = 0; c < 4; c++) {
      I4U v; v.v = src[c];
#pragma unroll
      for (int j = 0; j < 8; j++) {
        const int ij = q * 32 + c * 8 + j;
        *(short*)(xl + ij * 256 + ((2 * d) ^ ((ij & 7) << 4))) = (short)v.s[j];
      }
    }
  }
  __syncthreads();
  // ---- phase B: LN over d per ij row (4 threads/row)
  {
    const int row = t >> 2, seg = t & 3;
    char* base = xl + row * 256;
    const int sw = (row & 7) << 4;
    float f[32];
#pragma unroll
    for (int c = 0; c < 4; c++) {
      I4U v; v.v = *(const int4*)(base + ((seg * 64 + c * 16) ^ sw));
#pragma unroll
      for (int j = 0; j < 8; j++) f[c * 8 + j] = bf2f(v.s[j]);
    }
    float s = 0.f, ss = 0.f;
#pragma unroll
    for (int j = 0; j < 32; j++) { s += f[j]; ss += f[j] * f[j]; }
    s += __shfl_xor(s, 1); s += __shfl_xor(s, 2);
    ss += __shfl_xor(ss, 1); ss += __shfl_xor(ss, 2);
    const float mu = s * (1.f / 128.f);
    const float var = ss * (1.f / 128.f) - mu * mu;
    const float rs = rsqrtf(var + 1e-5f);
#pragma unroll
    for (int c = 0; c < 4; c++) {
      const float4 w0 = *(const float4*)(now_ + seg * 32 + c * 8);
      const float4 w1 = *(const float4*)(now_ + seg * 32 + c * 8 + 4);
      const float4 b0 = *(const float4*)(nob + seg * 32 + c * 8);
      const float4 b1 = *(const float4*)(nob + seg * 32 + c * 8 + 4);
      I4U o;
      o.s[0] = f2bf((f[c*8+0] - mu) * rs * w0.x + b0.x);
      o.s[1] = f2bf((f[c*8+1] - mu) * rs * w0.y + b0.y);
      o.s[2] = f2bf((f[c*8+2] - mu) * rs * w0.z + b0.z);
      o.s[3] = f2bf((f[c*8+3] - mu) * rs * w0.w + b0.w);
      o.s[4] = f2bf((f[c*8+4] - mu) * rs * w1.x + b1.x);
      o.s[5] = f2bf((f[c*8+5] - mu) * rs * w1.y + b1.y);
      o.s[6] = f2bf((f[c*8+6] - mu) * rs * w1.z + b1.z);
      o.s[7] = f2bf((f[c*8+7] - mu) * rs * w1.w + b1.w);
      *(int4*)(base + ((seg * 64 + c * 16) ^ sw)) = o.v;
    }
  }
  __syncthreads();
  // ---- phase C: out = (xln @ Wout^T) * gate
  const int wv = t >> 6, l = t & 63;
  const int l15 = l & 15, l4 = l >> 4;
  const int arow = wv * 16 + l15;
  const char* abase = xl + arow * 256;
  const int asw = (arow & 7) << 4;
  const char* wbase = (const char*)Wout + l15 * 256 + l4 * 16;
  f32x4 acc[8];
#pragma unroll
  for (int n = 0; n < 8; n++) acc[n] = (f32x4){0.f, 0.f, 0.f, 0.f};
#pragma unroll
  for (int ks = 0; ks < 4; ks++) {
    bf16x8 af = *(const bf16x8*)(abase + ((ks * 64 + l4 * 16) ^ asw));
#pragma unroll
    for (int n = 0; n < 8; n++) {
      bf16x8 bfr = *(const bf16x8*)(wbase + n * 4096 + ks * 64);
      acc[n] = __builtin_amdgcn_mfma_f32_16x16x32_bf16(af, bfr, acc[n], 0, 0, 0);
    }
  }
  const int rowb = wv * 16 + (l4 << 2);
#pragma unroll
  for (int n = 0; n < 8; n++) {
    const int e = n * 16 + l15;
#pragma unroll
    for (int r = 0; r < 4; r++) {
      const size_t idx = (size_t)(ij0 + rowb + r) * 128 + e;
      out[idx] = acc[n][r] * bf2f(gate[idx]);
    }
  }
}

// ---------------- launch ----------------
extern "C" void kernel_launch(void* const* d_in, const int* in_sizes, int n_in,
                              void* d_out, int out_size, void* d_ws, size_t ws_size,
                              hipStream_t stream) {
  const float* z    = (const float*)d_in[0];
  const float* mask = (const float*)d_in[1];
  const float* niw  = (const float*)d_in[2];
  const float* nib  = (const float*)d_in[3];
  const float* wp   = (const float*)d_in[4];
  const float* wg   = (const float*)d_in[5];
  const float* now_ = (const float*)d_in[6];
  const float* nob  = (const float*)d_in[7];
  const float* wo   = (const float*)d_in[8];
  const float* wga  = (const float*)d_in[9];
  float* out = (float*)d_out;
  char* ws = (char*)d_ws;

  u16* Wbig = (u16*)ws;                                   // 160 KB
  u16* Wout = (u16*)(ws + 0x28000);                       // 32 KB
  u16* a_t  = (u16*)(ws + 0x100000);                      // 64 MB  (D,N,N) bf16
  u16* b_t  = (u16*)(ws + 0x100000 + 0x4000000);          // 64 MB
  u16* x_t  = (u16*)(ws + 0x100000 + 0x8000000);          // 64 MB
  u16* gate = (u16*)(ws + 0x100000 + 0xC000000);          // 64 MB  (N*N, D) bf16

  hipLaunchKernelGGL(k_prep, dim3(384), dim3(256), 0, stream, wp, wg, wga, wo, Wbig, Wout);
  hipLaunchKernelGGL(k_pass1, dim3(4096), dim3(512), 0, stream, z, mask, niw, nib, Wbig, a_t, b_t, gate);
  hipLaunchKernelGGL(k_pass2, dim3(2048), dim3(256), 0, stream, a_t, b_t, x_t);
  hipLaunchKernelGGL(k_pass3, dim3(4096), dim3(256), 0, stream, x_t, gate, now_, nob, Wout, out);
  (void)in_sizes; (void)n_in; (void)out_size; (void)ws_size;
}

// Round 7
// 506.801 us; speedup vs baseline: 1.5332x; 1.3927x over previous
//
#include <hip/hip_runtime.h>
#include <cstdint>

#define NDIM 512
#define DDIM 128
#define NN (512 * 512)

typedef unsigned short u16;
typedef short bf16x8 __attribute__((ext_vector_type(8)));
typedef float f32x4 __attribute__((ext_vector_type(4)));

union I4U { int4 v; u16 s[8]; };

__device__ __forceinline__ u16 f2bf(float f) {
  unsigned u = __builtin_bit_cast(unsigned, f);
  u += 0x7fffu + ((u >> 16) & 1u);           // RNE
  return (u16)(u >> 16);
}
__device__ __forceinline__ float bf2f(u16 s) {
  return __builtin_bit_cast(float, ((unsigned)s) << 16);
}
__device__ __forceinline__ float sigm(float x) {
  return 1.0f / (1.0f + __expf(-x));
}
__device__ __forceinline__ unsigned cvtpk(float lo, float hi) {
  unsigned r;
  asm("v_cvt_pk_bf16_f32 %0, %1, %2" : "=v"(r) : "v"(lo), "v"(hi));
  return r;
}
__device__ __forceinline__ void gload16(void* lds_base, const void* gsrc) {
  __builtin_amdgcn_global_load_lds((const __attribute__((address_space(1))) void*)gsrc,
                                   (__attribute__((address_space(3))) void*)lds_base,
                                   16, 0, 0);
}

// ---------------- kernel 0: weights fp32 -> bf16 ----------------
// Wbig rows: [0,256)=wp, [256,512)=wg, [512,640)=w_gate. Wout = w_out. All [row][128].
__global__ __launch_bounds__(256) void k_prep(const float* __restrict__ wp,
                                              const float* __restrict__ wg,
                                              const float* __restrict__ wga,
                                              const float* __restrict__ wo,
                                              u16* __restrict__ Wbig, u16* __restrict__ Wout) {
  int i = blockIdx.x * 256 + threadIdx.x;    // 0..98303
  if (i < 640 * 128) {
    int r = i >> 7, c = i & 127;
    float v = (r < 256) ? wp[r * 128 + c] : (r < 512) ? wg[(r - 256) * 128 + c]
                                                      : wga[(r - 512) * 128 + c];
    Wbig[i] = f2bf(v);
  } else {
    int j = i - 640 * 128;                   // 0..16383
    Wout[j] = f2bf(wo[j]);
  }
}

// ---------------- kernel 1: LN(z) -> h; p,g,gate; a_t,b_t (d-major), gate ----------------
// 512 threads (8 waves). Weights staged to LDS in 10 x 16KB chunks, double-buffered
// via global_load_lds (pre-swizzled source, linear dest - m173 pattern). One barrier
// per chunk; stage(c+1) issued before compute(c) so L2 latency hides under MFMA+epi.
// LDS 80KB: [0,16K) h then gate-stage; [16K,48K) wbuf dbl; [48K,80K) ab-stage.
__global__ __launch_bounds__(512, 4) void k_pass1(
    const float* __restrict__ z, const float* __restrict__ mask,
    const float* __restrict__ niw, const float* __restrict__ nib,
    const u16* __restrict__ Wbig,
    u16* __restrict__ a_t, u16* __restrict__ b_t, u16* __restrict__ gate) {
  __shared__ __align__(16) char lds[81920];
  const int t = threadIdx.x;
  const int ij0 = blockIdx.x * 64;
  const int wv = t >> 6, l = t & 63;

  // chunk c tiles (4KB Wbig tiles of 16 e-rows each):
  //  c<8:  even=P-quarter, odd=G-quarter: base = ((c&1)<<4) + ((c>>1)<<2), tiles base..base+3
  //  c=8:  {32,33,36,37}; c=9: {34,35,38,39}  (gate, split so both wc-halves work)
  auto stage_chunk = [&](int c) {
    char* wb = lds + 16384 + (c & 1) * 16384;
#pragma unroll
    for (int r = 0; r < 2; ++r) {
      const int o = r * 8192 + t * 16;       // linear offset in 16KB chunk
      const int rowIT = (o >> 8) & 15;
      const int colb = o & 255;
      const int tsel = (o >> 12);            // 0..3
      int tile;
      if (c < 8) tile = ((c & 1) << 4) + ((c >> 1) << 2) + tsel;
      else       tile = 32 + ((c - 8) << 1) + (tsel & 1) + ((tsel >> 1) << 2);
      const char* src = (const char*)Wbig + tile * 4096 + rowIT * 256 +
                        (colb ^ ((rowIT & 7) << 4));
      gload16(wb + r * 8192 + wv * 1024, src);
    }
  };

  // ---- stage chunk 0 early (wbuf region free from start)
  stage_chunk(0);

  // ---- phase A: LN over D=128 per row; h -> lds[0:16K) as [64][256B] bf16, XOR-swizzled
  {
    const int row = t >> 3, seg = t & 7;     // 8 threads/row, 16 elems each
    const float4* zp = (const float4*)(z + (size_t)(ij0 + row) * 128 + seg * 16);
    float zv[16];
    {
      float4 a0 = zp[0], a1 = zp[1], a2 = zp[2], a3 = zp[3];
      zv[0]=a0.x; zv[1]=a0.y; zv[2]=a0.z; zv[3]=a0.w;
      zv[4]=a1.x; zv[5]=a1.y; zv[6]=a1.z; zv[7]=a1.w;
      zv[8]=a2.x; zv[9]=a2.y; zv[10]=a2.z; zv[11]=a2.w;
      zv[12]=a3.x; zv[13]=a3.y; zv[14]=a3.z; zv[15]=a3.w;
    }
    float s = 0.f, ss = 0.f;
#pragma unroll
    for (int j = 0; j < 16; j++) { s += zv[j]; ss += zv[j] * zv[j]; }
    s += __shfl_xor(s, 1); s += __shfl_xor(s, 2); s += __shfl_xor(s, 4);
    ss += __shfl_xor(ss, 1); ss += __shfl_xor(ss, 2); ss += __shfl_xor(ss, 4);
    const float mu = s * (1.f / 128.f);
    const float var = ss * (1.f / 128.f) - mu * mu;
    const float rs = rsqrtf(var + 1e-5f);
    float wv_[16], bv_[16];
    {
      const float4* wq = (const float4*)(niw + seg * 16);
      const float4* bq = (const float4*)(nib + seg * 16);
      float4 w0=wq[0],w1=wq[1],w2=wq[2],w3=wq[3], b0=bq[0],b1=bq[1],b2=bq[2],b3=bq[3];
      wv_[0]=w0.x;wv_[1]=w0.y;wv_[2]=w0.z;wv_[3]=w0.w; wv_[4]=w1.x;wv_[5]=w1.y;wv_[6]=w1.z;wv_[7]=w1.w;
      wv_[8]=w2.x;wv_[9]=w2.y;wv_[10]=w2.z;wv_[11]=w2.w; wv_[12]=w3.x;wv_[13]=w3.y;wv_[14]=w3.z;wv_[15]=w3.w;
      bv_[0]=b0.x;bv_[1]=b0.y;bv_[2]=b0.z;bv_[3]=b0.w; bv_[4]=b1.x;bv_[5]=b1.y;bv_[6]=b1.z;bv_[7]=b1.w;
      bv_[8]=b2.x;bv_[9]=b2.y;bv_[10]=b2.z;bv_[11]=b2.w; bv_[12]=b3.x;bv_[13]=b3.y;bv_[14]=b3.z;bv_[15]=b3.w;
    }
    I4U p0, p1;
#pragma unroll
    for (int j = 0; j < 4; j++) {
      unsigned w = cvtpk((zv[2*j] - mu) * rs * wv_[2*j] + bv_[2*j],
                         (zv[2*j+1] - mu) * rs * wv_[2*j+1] + bv_[2*j+1]);
      p0.s[2*j] = (u16)(w & 0xffff); p0.s[2*j+1] = (u16)(w >> 16);
    }
#pragma unroll
    for (int j = 0; j < 4; j++) {
      unsigned w = cvtpk((zv[8+2*j] - mu) * rs * wv_[8+2*j] + bv_[8+2*j],
                         (zv[9+2*j] - mu) * rs * wv_[9+2*j] + bv_[9+2*j]);
      p1.s[2*j] = (u16)(w & 0xffff); p1.s[2*j+1] = (u16)(w >> 16);
    }
    char* base = lds + row * 256;
    const int sw = (row & 7) << 4;
    *(int4*)(base + ((seg * 32) ^ sw)) = p0.v;
    *(int4*)(base + ((seg * 32 + 16) ^ sw)) = p1.v;
  }
  __syncthreads();   // h ready AND chunk0 staged (barrier drains vmcnt)

  const int wr = wv & 3, wc = wv >> 2;
  const int l15 = l & 15, l4 = l >> 4;

  // ---- A-fragments: load once, hold (16 VGPR); h-LDS dead afterwards
  const int arow = wr * 16 + l15;
  const char* abase = lds + arow * 256;
  const int asw = (arow & 7) << 4;
  bf16x8 af[4];
#pragma unroll
  for (int ks = 0; ks < 4; ks++)
    af[ks] = *(const bf16x8*)(abase + ((ks * 64 + l4 * 16) ^ asw));

  const int ijl = wr * 16 + l4 * 4;          // local row base (4 rows per lane)
  float mk[4];
#pragma unroll
  for (int r = 0; r < 4; r++) mk[r] = mask[ij0 + ijl + r];

  char* ab = lds + 49152;                    // ab-stage 32KB
  const int sw15 = (l15 & 7) << 4;
  f32x4 ap[2];

  // ---- 10 chunks: P0 G0 P1 G1 P2 G2 P3 G3 GA GB
#pragma unroll
  for (int c = 0; c < 10; ++c) {
    if (c < 9) stage_chunk(c + 1);
    const char* wb = lds + 16384 + (c & 1) * 16384;
    if (c < 8 && (c & 1) == 0) {
      // P-quarter: accumulate ap (kept across to the G-chunk)
#pragma unroll
      for (int s = 0; s < 2; ++s) {
        ap[s] = (f32x4){0.f, 0.f, 0.f, 0.f};
#pragma unroll
        for (int ks = 0; ks < 4; ++ks) {
          bf16x8 b = *(const bf16x8*)(wb + (2 * wc + s) * 4096 + l15 * 256 +
                                      ((ks * 64 + l4 * 16) ^ sw15));
          ap[s] = __builtin_amdgcn_mfma_f32_16x16x32_bf16(af[ks], b, ap[s], 0, 0, 0);
        }
      }
    } else if (c < 8) {
      // G-quarter: accumulate ag, fuse p*sigmoid(g)*mask, stage d-major
      const int q = c >> 1;
#pragma unroll
      for (int s = 0; s < 2; ++s) {
        f32x4 ag = (f32x4){0.f, 0.f, 0.f, 0.f};
#pragma unroll
        for (int ks = 0; ks < 4; ++ks) {
          bf16x8 b = *(const bf16x8*)(wb + (2 * wc + s) * 4096 + l15 * 256 +
                                      ((ks * 64 + l4 * 16) ^ sw15));
          ag = __builtin_amdgcn_mfma_f32_16x16x32_bf16(af[ks], b, ag, 0, 0, 0);
        }
        const int cl = 32 * wc + s * 16 + l15;
        unsigned w0 = cvtpk(ap[s][0] * sigm(ag[0]) * mk[0],
                            ap[s][1] * sigm(ag[1]) * mk[1]);
        unsigned w1 = cvtpk(ap[s][2] * sigm(ag[2]) * mk[2],
                            ap[s][3] * sigm(ag[3]) * mk[3]);
        unsigned long long uu = (unsigned long long)w0 | ((unsigned long long)w1 << 32);
        *(unsigned long long*)(ab + q * 8192 + cl * 128 + ((ijl * 2) ^ ((cl & 7) << 4))) = uu;
      }
    } else {
      if (c == 8) {
        // ab-stage complete (barrier after c=7): coalesced a_t/b_t global stores,
        // overlapped with the gate MFMAs below
        const int col = t >> 3, seg = t & 7;
        const int swc = (col & 7) << 4;
#pragma unroll
        for (int qq = 0; qq < 4; ++qq) {
          int4 v = *(const int4*)(ab + qq * 8192 + col * 128 + ((seg * 16) ^ swc));
          u16* dst = (qq < 2 ? a_t : b_t) + (size_t)((qq & 1) * 64 + col) * NN + ij0 + seg * 8;
          *(int4*)dst = v;
        }
      }
      // gate chunk: cols cbase + wc*64 + s*16 + l15; stage into h-region [0,16K)
      const int cbase = (c == 8) ? 0 : 32;
#pragma unroll
      for (int s = 0; s < 2; ++s) {
        f32x4 ag = (f32x4){0.f, 0.f, 0.f, 0.f};
#pragma unroll
        for (int ks = 0; ks < 4; ++ks) {
          bf16x8 b = *(const bf16x8*)(wb + (2 * wc + s) * 4096 + l15 * 256 +
                                      ((ks * 64 + l4 * 16) ^ sw15));
          ag = __builtin_amdgcn_mfma_f32_16x16x32_bf16(af[ks], b, ag, 0, 0, 0);
        }
        const int col2 = 2 * (cbase + wc * 64 + s * 16 + l15);
        unsigned w0 = cvtpk(sigm(ag[0]), sigm(ag[1]));
        unsigned w1 = cvtpk(sigm(ag[2]), sigm(ag[3]));
        *(u16*)(lds + (ijl + 0) * 256 + (col2 ^ (((ijl + 0) & 7) << 4))) = (u16)(w0 & 0xffff);
        *(u16*)(lds + (ijl + 1) * 256 + (col2 ^ (((ijl + 1) & 7) << 4))) = (u16)(w0 >> 16);
        *(u16*)(lds + (ijl + 2) * 256 + (col2 ^ (((ijl + 2) & 7) << 4))) = (u16)(w1 & 0xffff);
        *(u16*)(lds + (ijl + 3) * 256 + (col2 ^ (((ijl + 3) & 7) << 4))) = (u16)(w1 >> 16);
      }
    }
    __syncthreads();
  }

  // ---- coalesced gate store
  {
    const int row = t >> 3, seg = t & 7;
    const int sw = (row & 7) << 4;
    int4 v0 = *(const int4*)(lds + row * 256 + ((seg * 32) ^ sw));
    int4 v1 = *(const int4*)(lds + row * 256 + ((seg * 32 + 16) ^ sw));
    u16* gdst = gate + (size_t)(ij0 + row) * 128 + seg * 16;
    ((int4*)gdst)[0] = v0;
    ((int4*)gdst)[1] = v1;
  }
}

// ---------------- kernel 2: x_t[d] = a_t[d] @ b_t[d]^T, 128 batched 512^3 GEMMs ----------------
__global__ __launch_bounds__(256) void k_pass2(const u16* __restrict__ a_t,
                                               const u16* __restrict__ b_t,
                                               u16* __restrict__ x_t) {
  __shared__ __align__(16) char lds[32768];
  // XCD-chunked swizzle: nwg=2048 (divisible by 8) -> XCD x gets 16 consecutive d's
  const int b2 = ((int)blockIdx.x & 7) * 256 + ((int)blockIdx.x >> 3);
  const int d = b2 >> 4;
  const int tile = b2 & 15;
  const int row0 = (tile >> 2) * 128, col0 = (tile & 3) * 128;
  const char* A = (const char*)(a_t + (size_t)d * NN);
  const char* B = (const char*)(b_t + (size_t)d * NN);
  const int t = threadIdx.x;
  const int wv = t >> 6, l = t & 63;
  const int wr = wv >> 1, wc = wv & 1;
  const int l15 = l & 15, l4 = l >> 4;
  char* al = lds;
  char* bl = lds + 16384;
  f32x4 acc[4][4];
#pragma unroll
  for (int m = 0; m < 4; m++)
#pragma unroll
    for (int n = 0; n < 4; n++) acc[m][n] = (f32x4){0.f, 0.f, 0.f, 0.f};

  for (int ks = 0; ks < 8; ks++) {
#pragma unroll
    for (int it = 0; it < 4; it++) {
      const int f = it * 256 + t;            // t = wv*64 + l
      const int row = f >> 3, kc = f & 7;
      const int ldsoff = (it * 256 + wv * 64) * 16;   // wave-uniform base, lane adds l*16
      gload16(al + ldsoff, A + (size_t)(row0 + row) * 1024 + ks * 128 + kc * 16);
      gload16(bl + ldsoff, B + (size_t)(col0 + row) * 1024 + ks * 128 + kc * 16);
    }
    __syncthreads();
#pragma unroll
    for (int kk = 0; kk < 2; kk++) {
      bf16x8 af[4], bfr[4];
#pragma unroll
      for (int m = 0; m < 4; m++)
        af[m] = *(const bf16x8*)(al + (wr * 64 + m * 16 + l15) * 128 + kk * 64 + l4 * 16);
#pragma unroll
      for (int n = 0; n < 4; n++)
        bfr[n] = *(const bf16x8*)(bl + (wc * 64 + n * 16 + l15) * 128 + kk * 64 + l4 * 16);
#pragma unroll
      for (int m = 0; m < 4; m++)
#pragma unroll
        for (int n = 0; n < 4; n++)
          acc[m][n] = __builtin_amdgcn_mfma_f32_16x16x32_bf16(af[m], bfr[n], acc[m][n], 0, 0, 0);
    }
    __syncthreads();
  }
  // epilogue: stage C [128][256B] swizzled -> coalesced bf16 stores
#pragma unroll
  for (int m = 0; m < 4; m++) {
#pragma unroll
    for (int r = 0; r < 4; r++) {
      const int row = wr * 64 + m * 16 + l4 * 4 + r;
      const int sw = (row & 7) << 4;
      char* rowp = lds + row * 256;
#pragma unroll
      for (int n = 0; n < 4; n++) {
        const int col = wc * 64 + n * 16 + l15;
        *(short*)(rowp + ((col * 2) ^ sw)) = (short)f2bf(acc[m][n][r]);
      }
    }
  }
  __syncthreads();
  {
    const int row = t >> 1, q = t & 1;
    const int sw = (row & 7) << 4;
    const char* rowp = lds + row * 256;
    int4 v[8];
#pragma unroll
    for (int c = 0; c < 8; c++)
      v[c] = *(const int4*)(rowp + ((q * 128 + c * 16) ^ sw));
    u16* dst = x_t + (size_t)d * NN + (size_t)(row0 + row) * 512 + col0 + q * 64;
#pragma unroll
    for (int c = 0; c < 8; c++) ((int4*)dst)[c] = v[c];
  }
}

// ---------------- kernel 3: transpose x_t -> LN -> @w_out^T -> * gate ----------------
__global__ __launch_bounds__(256) void k_pass3(const u16* __restrict__ x_t,
                                               const u16* __restrict__ gate,
                                               const float* __restrict__ now_,
                                               const float* __restrict__ nob,
                                               const u16* __restrict__ Wout,
                                               float* __restrict__ out) {
  __shared__ __align__(16) char xl[16384];   // [64 ij][256B d] bf16, swizzled
  const int t = threadIdx.x;
  const int ij0 = blockIdx.x * 64;
  // ---- phase A: gather d-major -> (ij,d) LDS
  {
    const int d = t >> 1, q = t & 1;
    const int4* src = (const int4*)(x_t + (size_t)d * NN + ij0 + q * 32);
#pragma unroll
    for (int c = 0; c < 4; c++) {
      I4U v; v.v = src[c];
#pragma unroll
      for (int j = 0; j < 8; j++) {
        const int ij = q * 32 + c * 8 + j;
        *(short*)(xl + ij * 256 + ((2 * d) ^ ((ij & 7) << 4))) = (short)v.s[j];
      }
    }
  }
  __syncthreads();
  // ---- phase B: LN over d per ij row (4 threads/row)
  {
    const int row = t >> 2, seg = t & 3;
    char* base = xl + row * 256;
    const int sw = (row & 7) << 4;
    float f[32];
#pragma unroll
    for (int c = 0; c < 4; c++) {
      I4U v; v.v = *(const int4*)(base + ((seg * 64 + c * 16) ^ sw));
#pragma unroll
      for (int j = 0; j < 8; j++) f[c * 8 + j] = bf2f(v.s[j]);
    }
    float s = 0.f, ss = 0.f;
#pragma unroll
    for (int j = 0; j < 32; j++) { s += f[j]; ss += f[j] * f[j]; }
    s += __shfl_xor(s, 1); s += __shfl_xor(s, 2);
    ss += __shfl_xor(ss, 1); ss += __shfl_xor(ss, 2);
    const float mu = s * (1.f / 128.f);
    const float var = ss * (1.f / 128.f) - mu * mu;
    const float rs = rsqrtf(var + 1e-5f);
#pragma unroll
    for (int c = 0; c < 4; c++) {
      const float4 w0 = *(const float4*)(now_ + seg * 32 + c * 8);
      const float4 w1 = *(const float4*)(now_ + seg * 32 + c * 8 + 4);
      const float4 b0 = *(const float4*)(nob + seg * 32 + c * 8);
      const float4 b1 = *(const float4*)(nob + seg * 32 + c * 8 + 4);
      I4U o;
      o.s[0] = f2bf((f[c*8+0] - mu) * rs * w0.x + b0.x);
      o.s[1] = f2bf((f[c*8+1] - mu) * rs * w0.y + b0.y);
      o.s[2] = f2bf((f[c*8+2] - mu) * rs * w0.z + b0.z);
      o.s[3] = f2bf((f[c*8+3] - mu) * rs * w0.w + b0.w);
      o.s[4] = f2bf((f[c*8+4] - mu) * rs * w1.x + b1.x);
      o.s[5] = f2bf((f[c*8+5] - mu) * rs * w1.y + b1.y);
      o.s[6] = f2bf((f[c*8+6] - mu) * rs * w1.z + b1.z);
      o.s[7] = f2bf((f[c*8+7] - mu) * rs * w1.w + b1.w);
      *(int4*)(base + ((seg * 64 + c * 16) ^ sw)) = o.v;
    }
  }
  __syncthreads();
  // ---- phase C: out = (xln @ Wout^T) * gate
  const int wv = t >> 6, l = t & 63;
  const int l15 = l & 15, l4 = l >> 4;
  const int arow = wv * 16 + l15;
  const char* abase = xl + arow * 256;
  const int asw = (arow & 7) << 4;
  const char* wbase = (const char*)Wout + l15 * 256 + l4 * 16;
  f32x4 acc[8];
#pragma unroll
  for (int n = 0; n < 8; n++) acc[n] = (f32x4){0.f, 0.f, 0.f, 0.f};
#pragma unroll
  for (int ks = 0; ks < 4; ks++) {
    bf16x8 af = *(const bf16x8*)(abase + ((ks * 64 + l4 * 16) ^ asw));
#pragma unroll
    for (int n = 0; n < 8; n++) {
      bf16x8 bfr = *(const bf16x8*)(wbase + n * 4096 + ks * 64);
      acc[n] = __builtin_amdgcn_mfma_f32_16x16x32_bf16(af, bfr, acc[n], 0, 0, 0);
    }
  }
  const int rowb = wv * 16 + (l4 << 2);
#pragma unroll
  for (int n = 0; n < 8; n++) {
    const int e = n * 16 + l15;
#pragma unroll
    for (int r = 0; r < 4; r++) {
      const size_t idx = (size_t)(ij0 + rowb + r) * 128 + e;
      out[idx] = acc[n][r] * bf2f(gate[idx]);
    }
  }
}

// ---------------- launch ----------------
extern "C" void kernel_launch(void* const* d_in, const int* in_sizes, int n_in,
                              void* d_out, int out_size, void* d_ws, size_t ws_size,
                              hipStream_t stream) {
  const float* z    = (const float*)d_in[0];
  const float* mask = (const float*)d_in[1];
  const float* niw  = (const float*)d_in[2];
  const float* nib  = (const float*)d_in[3];
  const float* wp   = (const float*)d_in[4];
  const float* wg   = (const float*)d_in[5];
  const float* now_ = (const float*)d_in[6];
  const float* nob  = (const float*)d_in[7];
  const float* wo   = (const float*)d_in[8];
  const float* wga  = (const float*)d_in[9];
  float* out = (float*)d_out;
  char* ws = (char*)d_ws;

  u16* Wbig = (u16*)ws;                                   // 160 KB
  u16* Wout = (u16*)(ws + 0x28000);                       // 32 KB
  u16* a_t  = (u16*)(ws + 0x100000);                      // 64 MB  (D,N,N) bf16
  u16* b_t  = (u16*)(ws + 0x100000 + 0x4000000);          // 64 MB
  u16* x_t  = (u16*)(ws + 0x100000 + 0x8000000);          // 64 MB
  u16* gate = (u16*)(ws + 0x100000 + 0xC000000);          // 64 MB  (N*N, D) bf16

  hipLaunchKernelGGL(k_prep, dim3(384), dim3(256), 0, stream, wp, wg, wga, wo, Wbig, Wout);
  hipLaunchKernelGGL(k_pass1, dim3(4096), dim3(512), 0, stream, z, mask, niw, nib, Wbig, a_t, b_t, gate);
  hipLaunchKernelGGL(k_pass2, dim3(2048), dim3(256), 0, stream, a_t, b_t, x_t);
  hipLaunchKernelGGL(k_pass3, dim3(4096), dim3(256), 0, stream, x_t, gate, now_, nob, Wout, out);
  (void)in_sizes; (void)n_in; (void)out_size; (void)ws_size;
}

// Round 8
// 476.530 us; speedup vs baseline: 1.6306x; 1.0635x over previous
//
#include <hip/hip_runtime.h>
#include <cstdint>

#define NDIM 512
#define DDIM 128
#define NN (512 * 512)

typedef unsigned short u16;
typedef short bf16x8 __attribute__((ext_vector_type(8)));
typedef float f32x4 __attribute__((ext_vector_type(4)));
typedef unsigned long long u64;

union I4U { int4 v; u16 s[8]; };

__device__ __forceinline__ u16 f2bf(float f) {
  unsigned u = __builtin_bit_cast(unsigned, f);
  u += 0x7fffu + ((u >> 16) & 1u);           // RNE
  return (u16)(u >> 16);
}
__device__ __forceinline__ float bf2f(u16 s) {
  return __builtin_bit_cast(float, ((unsigned)s) << 16);
}
__device__ __forceinline__ float sigm(float x) {
  return 1.0f / (1.0f + __expf(-x));
}
__device__ __forceinline__ unsigned cvtpk(float lo, float hi) {
  unsigned r;
  asm("v_cvt_pk_bf16_f32 %0, %1, %2" : "=v"(r) : "v"(lo), "v"(hi));
  return r;
}
__device__ __forceinline__ void gload16(void* lds_base, const void* gsrc) {
  __builtin_amdgcn_global_load_lds((const __attribute__((address_space(1))) void*)gsrc,
                                   (__attribute__((address_space(3))) void*)lds_base,
                                   16, 0, 0);
}

// ---------------- kernel 0: weights fp32 -> bf16 ----------------
// Wbig rows: [0,256)=wp, [256,512)=wg, [512,640)=w_gate. Wout = w_out. All [row][128].
__global__ __launch_bounds__(256) void k_prep(const float* __restrict__ wp,
                                              const float* __restrict__ wg,
                                              const float* __restrict__ wga,
                                              const float* __restrict__ wo,
                                              u16* __restrict__ Wbig, u16* __restrict__ Wout) {
  int i = blockIdx.x * 256 + threadIdx.x;    // 0..98303
  if (i < 640 * 128) {
    int r = i >> 7, c = i & 127;
    float v = (r < 256) ? wp[r * 128 + c] : (r < 512) ? wg[(r - 256) * 128 + c]
                                                      : wga[(r - 512) * 128 + c];
    Wbig[i] = f2bf(v);
  } else {
    int j = i - 640 * 128;                   // 0..16383
    Wout[j] = f2bf(wo[j]);
  }
}

// ---------------- kernel 1: LN(z) -> h; p,g,gate; direct d-major stores ----------------
// 512 threads (8 waves). Weights staged to LDS in 10 x 16KB chunks, double-buffered
// via global_load_lds (pre-swizzled source, linear dest). One barrier per chunk.
// v4: ab and gate are stored DIRECTLY to global in d-major layout (8B per lane,
// 16 d-cols x 32B contiguous per inst; L2 merges half-lines) - no LDS round-trip.
// LDS 48KB: [0,16K) h; [16K,48K) wbuf dbl.
__global__ __launch_bounds__(512, 4) void k_pass1(
    const float* __restrict__ z, const float* __restrict__ mask,
    const float* __restrict__ niw, const float* __restrict__ nib,
    const u16* __restrict__ Wbig,
    u16* __restrict__ a_t, u16* __restrict__ b_t, u16* __restrict__ gate_t) {
  __shared__ __align__(16) char lds[49152];
  const int t = threadIdx.x;
  const int ij0 = blockIdx.x * 64;
  const int wv = t >> 6, l = t & 63;

  // chunk c tiles (4KB Wbig tiles of 16 e-rows each):
  //  c<8:  even=P-quarter, odd=G-quarter: base = ((c&1)<<4) + ((c>>1)<<2), tiles base..base+3
  //  c=8:  {32,33,36,37}; c=9: {34,35,38,39}  (gate, split so both wc-halves work)
  auto stage_chunk = [&](int c) {
    char* wb = lds + 16384 + (c & 1) * 16384;
#pragma unroll
    for (int r = 0; r < 2; ++r) {
      const int o = r * 8192 + t * 16;       // linear offset in 16KB chunk
      const int rowIT = (o >> 8) & 15;
      const int colb = o & 255;
      const int tsel = (o >> 12);            // 0..3
      int tile;
      if (c < 8) tile = ((c & 1) << 4) + ((c >> 1) << 2) + tsel;
      else       tile = 32 + ((c - 8) << 1) + (tsel & 1) + ((tsel >> 1) << 2);
      const char* src = (const char*)Wbig + tile * 4096 + rowIT * 256 +
                        (colb ^ ((rowIT & 7) << 4));
      gload16(wb + r * 8192 + wv * 1024, src);
    }
  };

  // ---- stage chunk 0 early (wbuf region free from start)
  stage_chunk(0);

  // ---- phase A: LN over D=128 per row; h -> lds[0:16K) as [64][256B] bf16, XOR-swizzled
  {
    const int row = t >> 3, seg = t & 7;     // 8 threads/row, 16 elems each
    const float4* zp = (const float4*)(z + (size_t)(ij0 + row) * 128 + seg * 16);
    float zv[16];
    {
      float4 a0 = zp[0], a1 = zp[1], a2 = zp[2], a3 = zp[3];
      zv[0]=a0.x; zv[1]=a0.y; zv[2]=a0.z; zv[3]=a0.w;
      zv[4]=a1.x; zv[5]=a1.y; zv[6]=a1.z; zv[7]=a1.w;
      zv[8]=a2.x; zv[9]=a2.y; zv[10]=a2.z; zv[11]=a2.w;
      zv[12]=a3.x; zv[13]=a3.y; zv[14]=a3.z; zv[15]=a3.w;
    }
    float s = 0.f, ss = 0.f;
#pragma unroll
    for (int j = 0; j < 16; j++) { s += zv[j]; ss += zv[j] * zv[j]; }
    s += __shfl_xor(s, 1); s += __shfl_xor(s, 2); s += __shfl_xor(s, 4);
    ss += __shfl_xor(ss, 1); ss += __shfl_xor(ss, 2); ss += __shfl_xor(ss, 4);
    const float mu = s * (1.f / 128.f);
    const float var = ss * (1.f / 128.f) - mu * mu;
    const float rs = rsqrtf(var + 1e-5f);
    float wv_[16], bv_[16];
    {
      const float4* wq = (const float4*)(niw + seg * 16);
      const float4* bq = (const float4*)(nib + seg * 16);
      float4 w0=wq[0],w1=wq[1],w2=wq[2],w3=wq[3], b0=bq[0],b1=bq[1],b2=bq[2],b3=bq[3];
      wv_[0]=w0.x;wv_[1]=w0.y;wv_[2]=w0.z;wv_[3]=w0.w; wv_[4]=w1.x;wv_[5]=w1.y;wv_[6]=w1.z;wv_[7]=w1.w;
      wv_[8]=w2.x;wv_[9]=w2.y;wv_[10]=w2.z;wv_[11]=w2.w; wv_[12]=w3.x;wv_[13]=w3.y;wv_[14]=w3.z;wv_[15]=w3.w;
      bv_[0]=b0.x;bv_[1]=b0.y;bv_[2]=b0.z;bv_[3]=b0.w; bv_[4]=b1.x;bv_[5]=b1.y;bv_[6]=b1.z;bv_[7]=b1.w;
      bv_[8]=b2.x;bv_[9]=b2.y;bv_[10]=b2.z;bv_[11]=b2.w; bv_[12]=b3.x;bv_[13]=b3.y;bv_[14]=b3.z;bv_[15]=b3.w;
    }
    I4U p0, p1;
#pragma unroll
    for (int j = 0; j < 4; j++) {
      unsigned w = cvtpk((zv[2*j] - mu) * rs * wv_[2*j] + bv_[2*j],
                         (zv[2*j+1] - mu) * rs * wv_[2*j+1] + bv_[2*j+1]);
      p0.s[2*j] = (u16)(w & 0xffff); p0.s[2*j+1] = (u16)(w >> 16);
    }
#pragma unroll
    for (int j = 0; j < 4; j++) {
      unsigned w = cvtpk((zv[8+2*j] - mu) * rs * wv_[8+2*j] + bv_[8+2*j],
                         (zv[9+2*j] - mu) * rs * wv_[9+2*j] + bv_[9+2*j]);
      p1.s[2*j] = (u16)(w & 0xffff); p1.s[2*j+1] = (u16)(w >> 16);
    }
    char* base = lds + row * 256;
    const int sw = (row & 7) << 4;
    *(int4*)(base + ((seg * 32) ^ sw)) = p0.v;
    *(int4*)(base + ((seg * 32 + 16) ^ sw)) = p1.v;
  }
  __syncthreads();   // h ready AND chunk0 staged (barrier drains vmcnt)

  const int wr = wv & 3, wc = wv >> 2;
  const int l15 = l & 15, l4 = l >> 4;

  // ---- A-fragments: load once, hold (16 VGPR)
  const int arow = wr * 16 + l15;
  const char* abase = lds + arow * 256;
  const int asw = (arow & 7) << 4;
  bf16x8 af[4];
#pragma unroll
  for (int ks = 0; ks < 4; ks++)
    af[ks] = *(const bf16x8*)(abase + ((ks * 64 + l4 * 16) ^ asw));

  const int ijl = wr * 16 + l4 * 4;          // local row base (4 rows per lane)
  float mk[4];
#pragma unroll
  for (int r = 0; r < 4; r++) mk[r] = mask[ij0 + ijl + r];

  const int sw15 = (l15 & 7) << 4;
  f32x4 ap[2];

  // ---- 10 chunks: P0 G0 P1 G1 P2 G2 P3 G3 GA GB
#pragma unroll
  for (int c = 0; c < 10; ++c) {
    if (c < 9) stage_chunk(c + 1);
    const char* wb = lds + 16384 + (c & 1) * 16384;
    if (c < 8 && (c & 1) == 0) {
      // P-quarter: accumulate ap (kept across to the G-chunk)
#pragma unroll
      for (int s = 0; s < 2; ++s) {
        ap[s] = (f32x4){0.f, 0.f, 0.f, 0.f};
#pragma unroll
        for (int ks = 0; ks < 4; ++ks) {
          bf16x8 b = *(const bf16x8*)(wb + (2 * wc + s) * 4096 + l15 * 256 +
                                      ((ks * 64 + l4 * 16) ^ sw15));
          ap[s] = __builtin_amdgcn_mfma_f32_16x16x32_bf16(af[ks], b, ap[s], 0, 0, 0);
        }
      }
    } else if (c < 8) {
      // G-quarter: accumulate ag, fuse p*sigmoid(g)*mask, store d-major DIRECT
      const int q = c >> 1;
#pragma unroll
      for (int s = 0; s < 2; ++s) {
        f32x4 ag = (f32x4){0.f, 0.f, 0.f, 0.f};
#pragma unroll
        for (int ks = 0; ks < 4; ++ks) {
          bf16x8 b = *(const bf16x8*)(wb + (2 * wc + s) * 4096 + l15 * 256 +
                                      ((ks * 64 + l4 * 16) ^ sw15));
          ag = __builtin_amdgcn_mfma_f32_16x16x32_bf16(af[ks], b, ag, 0, 0, 0);
        }
        const int e = q * 64 + 32 * wc + s * 16 + l15;   // e in [0,256)
        unsigned w0 = cvtpk(ap[s][0] * sigm(ag[0]) * mk[0],
                            ap[s][1] * sigm(ag[1]) * mk[1]);
        unsigned w1 = cvtpk(ap[s][2] * sigm(ag[2]) * mk[2],
                            ap[s][3] * sigm(ag[3]) * mk[3]);
        u64 uu = (u64)w0 | ((u64)w1 << 32);
        u16* dst = (e < 128 ? a_t + (size_t)e * NN
                            : b_t + (size_t)(e - 128) * NN) + ij0 + ijl;
        *(u64*)dst = uu;
      }
    } else {
      // gate chunk: cols cbase + wc*64 + s*16 + l15; store d-major DIRECT
      const int cbase = (c == 8) ? 0 : 32;
#pragma unroll
      for (int s = 0; s < 2; ++s) {
        f32x4 ag = (f32x4){0.f, 0.f, 0.f, 0.f};
#pragma unroll
        for (int ks = 0; ks < 4; ++ks) {
          bf16x8 b = *(const bf16x8*)(wb + (2 * wc + s) * 4096 + l15 * 256 +
                                      ((ks * 64 + l4 * 16) ^ sw15));
          ag = __builtin_amdgcn_mfma_f32_16x16x32_bf16(af[ks], b, ag, 0, 0, 0);
        }
        const int col = cbase + wc * 64 + s * 16 + l15;  // gate d-col 0..127
        unsigned w0 = cvtpk(sigm(ag[0]), sigm(ag[1]));
        unsigned w1 = cvtpk(sigm(ag[2]), sigm(ag[3]));
        u64 uu = (u64)w0 | ((u64)w1 << 32);
        *(u64*)(gate_t + (size_t)col * NN + ij0 + ijl) = uu;
      }
    }
    __syncthreads();
  }
}

// ---------------- kernel 2: x_t[d] = a_t[d] @ b_t[d]^T, 128 batched 512^3 GEMMs ----------------
__global__ __launch_bounds__(256) void k_pass2(const u16* __restrict__ a_t,
                                               const u16* __restrict__ b_t,
                                               u16* __restrict__ x_t) {
  __shared__ __align__(16) char lds[32768];
  // XCD-chunked swizzle: nwg=2048 (divisible by 8) -> XCD x gets 16 consecutive d's
  const int b2 = ((int)blockIdx.x & 7) * 256 + ((int)blockIdx.x >> 3);
  const int d = b2 >> 4;
  const int tile = b2 & 15;
  const int row0 = (tile >> 2) * 128, col0 = (tile & 3) * 128;
  const char* A = (const char*)(a_t + (size_t)d * NN);
  const char* B = (const char*)(b_t + (size_t)d * NN);
  const int t = threadIdx.x;
  const int wv = t >> 6, l = t & 63;
  const int wr = wv >> 1, wc = wv & 1;
  const int l15 = l & 15, l4 = l >> 4;
  char* al = lds;
  char* bl = lds + 16384;
  f32x4 acc[4][4];
#pragma unroll
  for (int m = 0; m < 4; m++)
#pragma unroll
    for (int n = 0; n < 4; n++) acc[m][n] = (f32x4){0.f, 0.f, 0.f, 0.f};

  for (int ks = 0; ks < 8; ks++) {
#pragma unroll
    for (int it = 0; it < 4; it++) {
      const int f = it * 256 + t;            // t = wv*64 + l
      const int row = f >> 3, kc = f & 7;
      const int ldsoff = (it * 256 + wv * 64) * 16;   // wave-uniform base, lane adds l*16
      gload16(al + ldsoff, A + (size_t)(row0 + row) * 1024 + ks * 128 + kc * 16);
      gload16(bl + ldsoff, B + (size_t)(col0 + row) * 1024 + ks * 128 + kc * 16);
    }
    __syncthreads();
#pragma unroll
    for (int kk = 0; kk < 2; kk++) {
      bf16x8 af[4], bfr[4];
#pragma unroll
      for (int m = 0; m < 4; m++)
        af[m] = *(const bf16x8*)(al + (wr * 64 + m * 16 + l15) * 128 + kk * 64 + l4 * 16);
#pragma unroll
      for (int n = 0; n < 4; n++)
        bfr[n] = *(const bf16x8*)(bl + (wc * 64 + n * 16 + l15) * 128 + kk * 64 + l4 * 16);
#pragma unroll
      for (int m = 0; m < 4; m++)
#pragma unroll
        for (int n = 0; n < 4; n++)
          acc[m][n] = __builtin_amdgcn_mfma_f32_16x16x32_bf16(af[m], bfr[n], acc[m][n], 0, 0, 0);
    }
    __syncthreads();
  }
  // epilogue: stage C [128][256B] swizzled -> coalesced bf16 stores
#pragma unroll
  for (int m = 0; m < 4; m++) {
#pragma unroll
    for (int r = 0; r < 4; r++) {
      const int row = wr * 64 + m * 16 + l4 * 4 + r;
      const int sw = (row & 7) << 4;
      char* rowp = lds + row * 256;
#pragma unroll
      for (int n = 0; n < 4; n++) {
        const int col = wc * 64 + n * 16 + l15;
        *(short*)(rowp + ((col * 2) ^ sw)) = (short)f2bf(acc[m][n][r]);
      }
    }
  }
  __syncthreads();
  {
    const int row = t >> 1, q = t & 1;
    const int sw = (row & 7) << 4;
    const char* rowp = lds + row * 256;
    int4 v[8];
#pragma unroll
    for (int c = 0; c < 8; c++)
      v[c] = *(const int4*)(rowp + ((q * 128 + c * 16) ^ sw));
    u16* dst = x_t + (size_t)d * NN + (size_t)(row0 + row) * 512 + col0 + q * 64;
#pragma unroll
    for (int c = 0; c < 8; c++) ((int4*)dst)[c] = v[c];
  }
}

// ---------------- kernel 3: transpose x_t -> LN -> @w_out^T -> * gate ----------------
// v2: (a) phase A = coalesced 8B d-major reads + in-register 8x4 transpose + b128
// LDS writes; (b) Wout staged once to LDS (pre-swizzled source, same recipe as
// pass1 weights); (c) gate read from d-major gate_t as 8B vectors (4 rows/load).
__global__ __launch_bounds__(256) void k_pass3(const u16* __restrict__ x_t,
                                               const u16* __restrict__ gate_t,
                                               const float* __restrict__ now_,
                                               const float* __restrict__ nob,
                                               const u16* __restrict__ Wout,
                                               float* __restrict__ out) {
  __shared__ __align__(16) char xl[16384];   // [64 ij][256B d] bf16, swizzled
  __shared__ __align__(16) char wl[32768];   // Wout [128 e][256B], swizzled
  const int t = threadIdx.x;
  const int ij0 = blockIdx.x * 64;
  const int wv = t >> 6;

  // ---- stage Wout -> wl (pre-swizzled source, linear dest)
#pragma unroll
  for (int r = 0; r < 8; ++r) {
    const int off = r * 4096 + t * 16;
    const int row = off >> 8, col = off & 255;
    gload16(wl + r * 4096 + wv * 1024,
            (const char*)Wout + row * 256 + (col ^ ((row & 7) << 4)));
  }

  // ---- phase A: coalesced gather + in-reg 8x4 transpose -> xl
  {
    const int iq = t & 15, o = t >> 4;       // iq: ij-quad, o: d-octet
    u64 rk[8];
#pragma unroll
    for (int k = 0; k < 8; ++k)
      rk[k] = *(const u64*)(x_t + (size_t)(o * 8 + k) * NN + ij0 + iq * 4);
#pragma unroll
    for (int i = 0; i < 4; ++i) {
      I4U ov;
#pragma unroll
      for (int k = 0; k < 8; ++k) ov.s[k] = (u16)(rk[k] >> (16 * i));
      const int ij = iq * 4 + i;
      *(int4*)(xl + ij * 256 + ((o * 16) ^ ((ij & 7) << 4))) = ov.v;
    }
  }
  __syncthreads();

  // ---- phase B: LN over d per ij row (4 threads/row)
  {
    const int row = t >> 2, seg = t & 3;
    char* base = xl + row * 256;
    const int sw = (row & 7) << 4;
    float f[32];
#pragma unroll
    for (int c = 0; c < 4; c++) {
      I4U v; v.v = *(const int4*)(base + ((seg * 64 + c * 16) ^ sw));
#pragma unroll
      for (int j = 0; j < 8; j++) f[c * 8 + j] = bf2f(v.s[j]);
    }
    float s = 0.f, ss = 0.f;
#pragma unroll
    for (int j = 0; j < 32; j++) { s += f[j]; ss += f[j] * f[j]; }
    s += __shfl_xor(s, 1); s += __shfl_xor(s, 2);
    ss += __shfl_xor(ss, 1); ss += __shfl_xor(ss, 2);
    const float mu = s * (1.f / 128.f);
    const float var = ss * (1.f / 128.f) - mu * mu;
    const float rs = rsqrtf(var + 1e-5f);
#pragma unroll
    for (int c = 0; c < 4; c++) {
      const float4 w0 = *(const float4*)(now_ + seg * 32 + c * 8);
      const float4 w1 = *(const float4*)(now_ + seg * 32 + c * 8 + 4);
      const float4 b0 = *(const float4*)(nob + seg * 32 + c * 8);
      const float4 b1 = *(const float4*)(nob + seg * 32 + c * 8 + 4);
      I4U o;
      unsigned q0 = cvtpk((f[c*8+0] - mu) * rs * w0.x + b0.x,
                          (f[c*8+1] - mu) * rs * w0.y + b0.y);
      unsigned q1 = cvtpk((f[c*8+2] - mu) * rs * w0.z + b0.z,
                          (f[c*8+3] - mu) * rs * w0.w + b0.w);
      unsigned q2 = cvtpk((f[c*8+4] - mu) * rs * w1.x + b1.x,
                          (f[c*8+5] - mu) * rs * w1.y + b1.y);
      unsigned q3 = cvtpk((f[c*8+6] - mu) * rs * w1.z + b1.z,
                          (f[c*8+7] - mu) * rs * w1.w + b1.w);
      o.s[0]=(u16)(q0&0xffff); o.s[1]=(u16)(q0>>16);
      o.s[2]=(u16)(q1&0xffff); o.s[3]=(u16)(q1>>16);
      o.s[4]=(u16)(q2&0xffff); o.s[5]=(u16)(q2>>16);
      o.s[6]=(u16)(q3&0xffff); o.s[7]=(u16)(q3>>16);
      *(int4*)(base + ((seg * 64 + c * 16) ^ sw)) = o.v;
    }
  }
  __syncthreads();

  // ---- phase C: out = (xln @ Wout^T) * gate
  const int l = t & 63;
  const int l15 = l & 15, l4 = l >> 4;
  const int arow = wv * 16 + l15;
  const char* abase = xl + arow * 256;
  const int asw = (arow & 7) << 4;
  f32x4 acc[8];
#pragma unroll
  for (int n = 0; n < 8; n++) acc[n] = (f32x4){0.f, 0.f, 0.f, 0.f};
#pragma unroll
  for (int ks = 0; ks < 4; ks++) {
    bf16x8 af = *(const bf16x8*)(abase + ((ks * 64 + l4 * 16) ^ asw));
#pragma unroll
    for (int n = 0; n < 8; n++) {
      const int erow = n * 16 + l15;
      bf16x8 bfr = *(const bf16x8*)(wl + erow * 256 +
                                    ((ks * 64 + l4 * 16) ^ ((erow & 7) << 4)));
      acc[n] = __builtin_amdgcn_mfma_f32_16x16x32_bf16(af, bfr, acc[n], 0, 0, 0);
    }
  }
  const int rowb = wv * 16 + (l4 << 2);
#pragma unroll
  for (int n = 0; n < 8; n++) {
    const int e = n * 16 + l15;
    const u64 g4 = *(const u64*)(gate_t + (size_t)e * NN + ij0 + rowb);
#pragma unroll
    for (int r = 0; r < 4; r++) {
      const size_t idx = (size_t)(ij0 + rowb + r) * 128 + e;
      out[idx] = acc[n][r] * bf2f((u16)(g4 >> (16 * r)));
    }
  }
}

// ---------------- launch ----------------
extern "C" void kernel_launch(void* const* d_in, const int* in_sizes, int n_in,
                              void* d_out, int out_size, void* d_ws, size_t ws_size,
                              hipStream_t stream) {
  const float* z    = (const float*)d_in[0];
  const float* mask = (const float*)d_in[1];
  const float* niw  = (const float*)d_in[2];
  const float* nib  = (const float*)d_in[3];
  const float* wp   = (const float*)d_in[4];
  const float* wg   = (const float*)d_in[5];
  const float* now_ = (const float*)d_in[6];
  const float* nob  = (const float*)d_in[7];
  const float* wo   = (const float*)d_in[8];
  const float* wga  = (const float*)d_in[9];
  float* out = (float*)d_out;
  char* ws = (char*)d_ws;

  u16* Wbig = (u16*)ws;                                   // 160 KB
  u16* Wout = (u16*)(ws + 0x28000);                       // 32 KB
  u16* a_t  = (u16*)(ws + 0x100000);                      // 64 MB  (D,N,N) bf16
  u16* b_t  = (u16*)(ws + 0x100000 + 0x4000000);          // 64 MB
  u16* x_t  = (u16*)(ws + 0x100000 + 0x8000000);          // 64 MB
  u16* gate = (u16*)(ws + 0x100000 + 0xC000000);          // 64 MB  (D, N*N) bf16 d-major

  hipLaunchKernelGGL(k_prep, dim3(384), dim3(256), 0, stream, wp, wg, wga, wo, Wbig, Wout);
  hipLaunchKernelGGL(k_pass1, dim3(4096), dim3(512), 0, stream, z, mask, niw, nib, Wbig, a_t, b_t, gate);
  hipLaunchKernelGGL(k_pass2, dim3(2048), dim3(256), 0, stream, a_t, b_t, x_t);
  hipLaunchKernelGGL(k_pass3, dim3(4096), dim3(256), 0, stream, x_t, gate, now_, nob, Wout, out);
  (void)in_sizes; (void)n_in; (void)out_size; (void)ws_size;
}